// Round 1
// baseline (479.393 us; speedup 1.0000x reference)
//
#include <hip/hip_runtime.h>

typedef __attribute__((ext_vector_type(4)))  float f32x4;
typedef __attribute__((ext_vector_type(16))) float f32x16;
typedef __attribute__((ext_vector_type(8)))  short s16x8;

// B=512, T=256, E=384, H=64.  M = B*T = 131072 rows.

__device__ inline short f2bf(float f){
  unsigned u = __float_as_uint(f);
  u = u + 0x7fffu + ((u >> 16) & 1u);   // round-to-nearest-even
  return (short)(u >> 16);
}

// ---------------- Kernel 0: Wt[n][k] = W_{n/64}[k][n%64]  (bf16) ----------------
__global__ void wt_prep_kernel(const float* __restrict__ Wq, const float* __restrict__ Wk,
                               const float* __restrict__ Wv, short* __restrict__ Wt){
  int o = blockIdx.x * 256 + threadIdx.x;
  if (o >= 192*384) return;
  int n = o / 384, k = o - n*384;
  const float* W = (n < 64) ? Wq : (n < 128) ? Wk : Wv;
  Wt[o] = f2bf(W[k*64 + (n & 63)]);
}

// ---------------- Kernel 1: QKV projection (bf16 MFMA 32x32x16) ----------------
// block = 256 thr (4 waves), BM=128 rows, N=192 (Q|K|V), K-tiles of 64.
// A frags straight from global fp32 + in-register cvt; Wt tile staged in LDS.
__global__ __launch_bounds__(256) void proj_kernel(const float* __restrict__ x, const short* __restrict__ Wt,
                            short* __restrict__ Q, short* __restrict__ K, short* __restrict__ Vt){
  __shared__ __align__(16) short Bt[192*72];   // [n][k] stride 72 (36 dw = 4 mod 32: conflict-free)
  const int tid  = threadIdx.x;
  const int wave = tid >> 6, lane = tid & 63;
  const int l31  = lane & 31, hh = lane >> 5;
  const long row0  = (long)blockIdx.x * 128;
  const long myrow = row0 + wave*32 + l31;

  f32x16 acc[6];
  #pragma unroll
  for (int c = 0; c < 6; ++c)
    #pragma unroll
    for (int j = 0; j < 16; ++j) acc[c][j] = 0.0f;

  for (int kt = 0; kt < 6; ++kt){
    const int k0 = kt*64;
    #pragma unroll
    for (int i = 0; i < 6; ++i){              // stage Wt[0..191][k0..k0+63]
      int c = tid + i*256;                    // 0..1535
      int n = c >> 3, co = (c & 7) * 8;
      s16x8 wv = *(const s16x8*)(Wt + n*384 + k0 + co);
      *(s16x8*)(Bt + n*72 + co) = wv;
    }
    __syncthreads();
    #pragma unroll
    for (int s = 0; s < 4; ++s){              // 4 mfma K-steps of 16
      const float* xp = x + myrow*384 + (k0 + s*16 + hh*8);
      float4 a0 = *(const float4*)xp;
      float4 a1 = *(const float4*)(xp + 4);
      s16x8 af;
      af[0]=f2bf(a0.x); af[1]=f2bf(a0.y); af[2]=f2bf(a0.z); af[3]=f2bf(a0.w);
      af[4]=f2bf(a1.x); af[5]=f2bf(a1.y); af[6]=f2bf(a1.z); af[7]=f2bf(a1.w);
      #pragma unroll
      for (int c = 0; c < 6; ++c){
        s16x8 bfr = *(const s16x8*)(Bt + (c*32 + l31)*72 + s*16 + hh*8);
        acc[c] = __builtin_amdgcn_mfma_f32_32x32x16_bf16(af, bfr, acc[c], 0, 0, 0);
      }
    }
    __syncthreads();
  }
  // epilogue: C layout 32x32: col = lane&31, row = (reg&3) + 8*(reg>>2) + 4*(lane>>5)
  #pragma unroll
  for (int c = 0; c < 6; ++c){
    const int n = c*32 + l31;
    #pragma unroll
    for (int reg = 0; reg < 16; ++reg){
      const int  rowC = (reg & 3) + 8*(reg >> 2) + 4*hh;
      const long r    = row0 + wave*32 + rowC;
      const short v   = f2bf(acc[c][reg]);
      if (n < 64)       Q[r*64 + n] = v;
      else if (n < 128) K[r*64 + (n - 64)] = v;
      else              Vt[(r >> 8)*16384 + (long)(n - 128)*256 + (r & 255)] = v;  // [b][h][t]
    }
  }
}

// ---------------- Kernel 2: causal attention (bf16 MFMA 16x16x32) ----------------
// block = (b, qtile of 64), 4 waves x 16 queries. K/Vt frags direct-from-global
// (L1/L2 hot). P round-trips through 1.25KB/wave LDS (C-layout -> A-layout).
__global__ __launch_bounds__(256) void attn_kernel(const short* __restrict__ Q, const short* __restrict__ K,
                            const short* __restrict__ Vt, float* __restrict__ out){
  __shared__ __align__(16) short P[4][16*40];  // per-wave 16 x 32 chunk, stride 40 (16B-aligned rows)
  const int tid  = threadIdx.x;
  const int w    = tid >> 6, lane = tid & 63;
  const int l15  = lane & 15, quad = lane >> 4;
  const int b    = blockIdx.x >> 2, qt = blockIdx.x & 3;
  const int qbase = qt*64 + w*16;
  const int NFw  = (qbase >> 4) + 1;           // causal: key frags needed by this wave
  const int NSw  = (NFw + 1) >> 1;             // 32-key PV steps

  const short* Qs = Q  + ((long)b*256 + qbase)*64;
  const short* Ks = K  + (long)b*256*64;
  const short* Vs = Vt + (long)b*64*256;

  // A frags: A[m=lane&15][k=(lane>>4)*8+j]
  s16x8 qf0 = *(const s16x8*)(Qs + l15*64 + quad*8);
  s16x8 qf1 = *(const s16x8*)(Qs + l15*64 + 32 + quad*8);

  f32x4 sc[16];
  #pragma unroll
  for (int f = 0; f < 16; ++f)
    #pragma unroll
    for (int r = 0; r < 4; ++r) sc[f][r] = 0.0f;

  #pragma unroll
  for (int f = 0; f < 16; ++f){
    if (f >= NFw) break;
    const short* kp = Ks + (f*16 + l15)*64 + quad*8;   // B[k][n=key]: K row-major works
    s16x8 k0v = *(const s16x8*)kp;
    s16x8 k1v = *(const s16x8*)(kp + 32);
    f32x4 a;
    #pragma unroll
    for (int r = 0; r < 4; ++r) a[r] = 0.0f;
    a = __builtin_amdgcn_mfma_f32_16x16x32_bf16(qf0, k0v, a, 0, 0, 0);
    a = __builtin_amdgcn_mfma_f32_16x16x32_bf16(qf1, k1v, a, 0, 0, 0);
    sc[f] = a;
  }

  // softmax: C layout col=key=f*16+(lane&15), row=query=quad*4+reg
  float mx[4], sm[4];
  #pragma unroll
  for (int r = 0; r < 4; ++r) mx[r] = -3.0e38f;
  #pragma unroll
  for (int f = 0; f < 16; ++f){
    if (f >= NFw) break;
    const int key = f*16 + l15;
    #pragma unroll
    for (int r = 0; r < 4; ++r){
      const int qg = qbase + quad*4 + r;
      float s = sc[f][r] * 0.125f;               // d^-0.5, H=64
      s = (key <= qg) ? s : -1.0e30f;
      sc[f][r] = s;
      mx[r] = fmaxf(mx[r], s);
    }
  }
  #pragma unroll
  for (int r = 0; r < 4; ++r){
    #pragma unroll
    for (int off = 1; off < 16; off <<= 1) mx[r] = fmaxf(mx[r], __shfl_xor(mx[r], off, 16));
  }
  #pragma unroll
  for (int r = 0; r < 4; ++r) sm[r] = 0.0f;
  #pragma unroll
  for (int f = 0; f < 16; ++f){
    if (f >= NFw) break;
    #pragma unroll
    for (int r = 0; r < 4; ++r){
      float p = exp2f((sc[f][r] - mx[r]) * 1.44269504f);
      sc[f][r] = p;
      sm[r] += p;
    }
  }
  #pragma unroll
  for (int r = 0; r < 4; ++r){
    #pragma unroll
    for (int off = 1; off < 16; off <<= 1) sm[r] += __shfl_xor(sm[r], off, 16);
  }

  // PV: out[16q x 64h], A = P via LDS round-trip, B = Vt rows (8 consecutive k/lane)
  f32x4 o[4];
  #pragma unroll
  for (int h = 0; h < 4; ++h)
    #pragma unroll
    for (int r = 0; r < 4; ++r) o[h][r] = 0.0f;

  short* Pw = P[w];
  #pragma unroll
  for (int ks = 0; ks < 8; ++ks){
    if (ks >= NSw) break;
    #pragma unroll
    for (int fi = 0; fi < 2; ++fi){
      const int f = 2*ks + fi;
      #pragma unroll
      for (int r = 0; r < 4; ++r){
        short v = 0;
        if (f < NFw) v = f2bf(sc[f][r]);
        Pw[(quad*4 + r)*40 + fi*16 + l15] = v;
      }
    }
    s16x8 pf = *(const s16x8*)(Pw + l15*40 + quad*8);  // A[m=l15][k=quad*8+j]
    #pragma unroll
    for (int h = 0; h < 4; ++h){
      s16x8 vf = *(const s16x8*)(Vs + (h*16 + l15)*256 + ks*32 + quad*8);
      o[h] = __builtin_amdgcn_mfma_f32_16x16x32_bf16(pf, vf, o[h], 0, 0, 0);
    }
  }

  float* op = out + ((long)b*256 + qbase)*64;
  #pragma unroll
  for (int r = 0; r < 4; ++r){
    const float inv = 1.0f / sm[r];
    #pragma unroll
    for (int h = 0; h < 4; ++h)
      op[(quad*4 + r)*64 + h*16 + l15] = o[h][r] * inv;
  }
}

extern "C" void kernel_launch(void* const* d_in, const int* in_sizes, int n_in,
                              void* d_out, int out_size, void* d_ws, size_t ws_size,
                              hipStream_t stream){
  const float* x  = (const float*)d_in[0];
  const float* Wq = (const float*)d_in[1];
  const float* Wk = (const float*)d_in[2];
  const float* Wv = (const float*)d_in[3];
  float* out = (float*)d_out;

  char* ws = (char*)d_ws;
  short* Wt = (short*)ws;                                  // 192*384*2      = 147456 B
  short* Q  = (short*)(ws + 147456);                       // 131072*64*2    = 16.78 MB
  short* K  = (short*)(ws + 147456 + 16777216);
  short* Vt = (short*)(ws + 147456 + 2*16777216);          // [b][h][t], total ws ~50.5 MB

  hipLaunchKernelGGL(wt_prep_kernel, dim3(288),  dim3(256), 0, stream, Wq, Wk, Wv, Wt);
  hipLaunchKernelGGL(proj_kernel,    dim3(1024), dim3(256), 0, stream, x, Wt, Q, K, Vt);
  hipLaunchKernelGGL(attn_kernel,    dim3(2048), dim3(256), 0, stream, Q, K, Vt, out);
}

// Round 2
// 389.623 us; speedup vs baseline: 1.2304x; 1.2304x over previous
//
#include <hip/hip_runtime.h>

typedef __attribute__((ext_vector_type(4)))  float f32x4;
typedef __attribute__((ext_vector_type(16))) float f32x16;
typedef __attribute__((ext_vector_type(8)))  short s16x8;

// B=512, T=256, E=384, H=64.  M = B*T = 131072 rows.

__device__ inline short f2bf(float f){
  unsigned u = __float_as_uint(f);
  u = u + 0x7fffu + ((u >> 16) & 1u);   // round-to-nearest-even
  return (short)(u >> 16);
}

// ---------------- Kernel 0: Wt[n][k] = W_{n/64}[k][n%64]  (bf16) ----------------
__global__ void wt_prep_kernel(const float* __restrict__ Wq, const float* __restrict__ Wk,
                               const float* __restrict__ Wv, short* __restrict__ Wt){
  int o = blockIdx.x * 256 + threadIdx.x;
  if (o >= 192*384) return;
  int n = o / 384, k = o - n*384;
  const float* W = (n < 64) ? Wq : (n < 128) ? Wk : Wv;
  Wt[o] = f2bf(W[k*64 + (n & 63)]);
}

// ---------------- Kernel 1: QKV projection (bf16 MFMA 32x32x16) ----------------
__global__ __launch_bounds__(256) void proj_kernel(const float* __restrict__ x, const short* __restrict__ Wt,
                            short* __restrict__ Q, short* __restrict__ K, short* __restrict__ Vt){
  __shared__ __align__(16) short Bt[192*72];   // [n][k] stride 72 (36 dw = 4 mod 32: conflict-free)
  const int tid  = threadIdx.x;
  const int wave = tid >> 6, lane = tid & 63;
  const int l31  = lane & 31, hh = lane >> 5;
  const long row0  = (long)blockIdx.x * 128;
  const long myrow = row0 + wave*32 + l31;

  f32x16 acc[6];
  #pragma unroll
  for (int c = 0; c < 6; ++c)
    #pragma unroll
    for (int j = 0; j < 16; ++j) acc[c][j] = 0.0f;

  for (int kt = 0; kt < 6; ++kt){
    const int k0 = kt*64;
    #pragma unroll
    for (int i = 0; i < 6; ++i){              // stage Wt[0..191][k0..k0+63]
      int c = tid + i*256;                    // 0..1535
      int n = c >> 3, co = (c & 7) * 8;
      s16x8 wv = *(const s16x8*)(Wt + n*384 + k0 + co);
      *(s16x8*)(Bt + n*72 + co) = wv;
    }
    __syncthreads();
    #pragma unroll
    for (int s = 0; s < 4; ++s){              // 4 mfma K-steps of 16
      const float* xp = x + myrow*384 + (k0 + s*16 + hh*8);
      float4 a0 = *(const float4*)xp;
      float4 a1 = *(const float4*)(xp + 4);
      s16x8 af;
      af[0]=f2bf(a0.x); af[1]=f2bf(a0.y); af[2]=f2bf(a0.z); af[3]=f2bf(a0.w);
      af[4]=f2bf(a1.x); af[5]=f2bf(a1.y); af[6]=f2bf(a1.z); af[7]=f2bf(a1.w);
      #pragma unroll
      for (int c = 0; c < 6; ++c){
        s16x8 bfr = *(const s16x8*)(Bt + (c*32 + l31)*72 + s*16 + hh*8);
        acc[c] = __builtin_amdgcn_mfma_f32_32x32x16_bf16(af, bfr, acc[c], 0, 0, 0);
      }
    }
    __syncthreads();
  }
  // epilogue: C layout 32x32: col = lane&31, row = (reg&3) + 8*(reg>>2) + 4*(lane>>5)
  #pragma unroll
  for (int c = 0; c < 6; ++c){
    const int n = c*32 + l31;
    #pragma unroll
    for (int reg = 0; reg < 16; ++reg){
      const int  rowC = (reg & 3) + 8*(reg >> 2) + 4*hh;
      const long r    = row0 + wave*32 + rowC;
      const short v   = f2bf(acc[c][reg]);
      if (n < 64)       Q[r*64 + n] = v;
      else if (n < 128) K[r*64 + (n - 64)] = v;
      else              Vt[(r >> 8)*16384 + (long)(n - 128)*256 + (r & 255)] = v;  // [b][h][t]
    }
  }
}

// ---------------- Kernel 2: causal attention (bf16 MFMA 16x16x32) ----------------
// block = (b, qtile of 64), 4 waves x 16 queries. K/Vt frags direct-from-global
// (L1/L2 hot). P round-trips through 1.25KB/wave LDS (C-layout -> A-layout).
// R2 fix: ALL register-array loops have compile-time trip counts with
// wave-uniform `if (f < NFw)` guards — no `break` — so sc[] stays in VGPRs
// (R1: break blocked unrolling -> sc spilled to scratch -> 360MB HBM writes).
__global__ __launch_bounds__(256) void attn_kernel(const short* __restrict__ Q, const short* __restrict__ K,
                            const short* __restrict__ Vt, float* __restrict__ out){
  __shared__ __align__(16) short P[4][16*40];  // per-wave 16 x 32 chunk, stride 40 (16B-aligned rows)
  const int tid  = threadIdx.x;
  const int w    = tid >> 6, lane = tid & 63;
  const int l15  = lane & 15, quad = lane >> 4;
  const int b    = blockIdx.x >> 2, qt = blockIdx.x & 3;
  const int qbase = qt*64 + w*16;
  const int NFw  = (qbase >> 4) + 1;           // causal: key frags needed by this wave (1..16)
  const int NSw  = (NFw + 1) >> 1;             // 32-key PV steps (1..8)

  const short* Qs = Q  + ((long)b*256 + qbase)*64;
  const short* Ks = K  + (long)b*256*64;
  const short* Vs = Vt + (long)b*64*256;

  // A frags: A[m=lane&15][k=(lane>>4)*8+j]
  s16x8 qf0 = *(const s16x8*)(Qs + l15*64 + quad*8);
  s16x8 qf1 = *(const s16x8*)(Qs + l15*64 + 32 + quad*8);

  f32x4 sc[16];
  #pragma unroll
  for (int f = 0; f < 16; ++f){
    f32x4 a;
    #pragma unroll
    for (int r = 0; r < 4; ++r) a[r] = 0.0f;
    if (f < NFw){
      const short* kp = Ks + (f*16 + l15)*64 + quad*8;   // B[k][n=key]: K row-major works
      s16x8 k0v = *(const s16x8*)kp;
      s16x8 k1v = *(const s16x8*)(kp + 32);
      a = __builtin_amdgcn_mfma_f32_16x16x32_bf16(qf0, k0v, a, 0, 0, 0);
      a = __builtin_amdgcn_mfma_f32_16x16x32_bf16(qf1, k1v, a, 0, 0, 0);
    }
    sc[f] = a;
  }

  // softmax: C layout col=key=f*16+(lane&15), row=query=quad*4+reg
  float mx[4], sm[4];
  #pragma unroll
  for (int r = 0; r < 4; ++r) mx[r] = -3.0e38f;
  #pragma unroll
  for (int f = 0; f < 16; ++f){
    if (f < NFw){
      const int key = f*16 + l15;
      #pragma unroll
      for (int r = 0; r < 4; ++r){
        const int qg = qbase + quad*4 + r;
        float s = sc[f][r] * 0.125f;               // d^-0.5, H=64
        s = (key <= qg) ? s : -1.0e30f;
        sc[f][r] = s;
        mx[r] = fmaxf(mx[r], s);
      }
    }
  }
  #pragma unroll
  for (int r = 0; r < 4; ++r){
    #pragma unroll
    for (int off = 1; off < 16; off <<= 1) mx[r] = fmaxf(mx[r], __shfl_xor(mx[r], off, 16));
  }
  #pragma unroll
  for (int r = 0; r < 4; ++r) sm[r] = 0.0f;
  #pragma unroll
  for (int f = 0; f < 16; ++f){
    if (f < NFw){
      #pragma unroll
      for (int r = 0; r < 4; ++r){
        float p = exp2f((sc[f][r] - mx[r]) * 1.44269504f);
        sc[f][r] = p;
        sm[r] += p;
      }
    }
  }
  #pragma unroll
  for (int r = 0; r < 4; ++r){
    #pragma unroll
    for (int off = 1; off < 16; off <<= 1) sm[r] += __shfl_xor(sm[r], off, 16);
  }

  // PV: out[16q x 64h], A = P via LDS round-trip, B = Vt rows (8 consecutive k/lane)
  f32x4 o[4];
  #pragma unroll
  for (int h = 0; h < 4; ++h)
    #pragma unroll
    for (int r = 0; r < 4; ++r) o[h][r] = 0.0f;

  short* Pw = P[w];
  #pragma unroll
  for (int ks = 0; ks < 8; ++ks){
    if (ks < NSw){
      #pragma unroll
      for (int fi = 0; fi < 2; ++fi){
        const int f = 2*ks + fi;
        #pragma unroll
        for (int r = 0; r < 4; ++r){
          short v = 0;
          if (f < NFw) v = f2bf(sc[f][r]);
          Pw[(quad*4 + r)*40 + fi*16 + l15] = v;
        }
      }
      s16x8 pf = *(const s16x8*)(Pw + l15*40 + quad*8);  // A[m=l15][k=quad*8+j]
      #pragma unroll
      for (int h = 0; h < 4; ++h){
        s16x8 vf = *(const s16x8*)(Vs + (h*16 + l15)*256 + ks*32 + quad*8);
        o[h] = __builtin_amdgcn_mfma_f32_16x16x32_bf16(pf, vf, o[h], 0, 0, 0);
      }
    }
  }

  float* op = out + ((long)b*256 + qbase)*64;
  #pragma unroll
  for (int r = 0; r < 4; ++r){
    const float inv = 1.0f / sm[r];
    #pragma unroll
    for (int h = 0; h < 4; ++h)
      op[(quad*4 + r)*64 + h*16 + l15] = o[h][r] * inv;
  }
}

extern "C" void kernel_launch(void* const* d_in, const int* in_sizes, int n_in,
                              void* d_out, int out_size, void* d_ws, size_t ws_size,
                              hipStream_t stream){
  const float* x  = (const float*)d_in[0];
  const float* Wq = (const float*)d_in[1];
  const float* Wk = (const float*)d_in[2];
  const float* Wv = (const float*)d_in[3];
  float* out = (float*)d_out;

  char* ws = (char*)d_ws;
  short* Wt = (short*)ws;                                  // 192*384*2      = 147456 B
  short* Q  = (short*)(ws + 147456);                       // 131072*64*2    = 16.78 MB
  short* K  = (short*)(ws + 147456 + 16777216);
  short* Vt = (short*)(ws + 147456 + 2*16777216);          // [b][h][t], total ws ~50.5 MB

  hipLaunchKernelGGL(wt_prep_kernel, dim3(288),  dim3(256), 0, stream, Wq, Wk, Wv, Wt);
  hipLaunchKernelGGL(proj_kernel,    dim3(1024), dim3(256), 0, stream, x, Wt, Q, K, Vt);
  hipLaunchKernelGGL(attn_kernel,    dim3(2048), dim3(256), 0, stream, Q, K, Vt, out);
}

// Round 3
// 361.819 us; speedup vs baseline: 1.3250x; 1.0768x over previous
//
#include <hip/hip_runtime.h>

typedef __attribute__((ext_vector_type(4)))  float f32x4;
typedef __attribute__((ext_vector_type(16))) float f32x16;
typedef __attribute__((ext_vector_type(8)))  short s16x8;
typedef __attribute__((ext_vector_type(4)))  short s16x4;

// B=512, T=256, E=384, H=64.

__device__ inline short f2bf(float f){
  unsigned u = __float_as_uint(f);
  u = u + 0x7fffu + ((u >> 16) & 1u);   // round-to-nearest-even
  return (short)(u >> 16);
}

// ---------------- Kernel 0: Wt[n][k] = W_{n/64}[k][n%64]  (bf16) ----------------
__global__ void wt_prep_kernel(const float* __restrict__ Wq, const float* __restrict__ Wk,
                               const float* __restrict__ Wv, short* __restrict__ Wt){
  int o = blockIdx.x * 256 + threadIdx.x;
  if (o >= 192*384) return;
  int n = o / 384, k = o - n*384;
  const float* W = (n < 64) ? Wq : (n < 128) ? Wk : Wv;
  Wt[o] = f2bf(W[k*64 + (n & 63)]);
}

// ---------------- Fused QKV-projection + causal attention ----------------
// 1 block = 1 batch. 8 waves. Phase 1: wave w projects rows [32w,32w+32):
// operand-swapped MFMA (A = Wt chunk from global/L1, B = x rows, contiguous)
// -> NO barriers in the K loop, x loads pipeline freely. C[m=outcol][n=row].
// Results land in LDS (Q/K row-major pad-72; V transposed [h][t] pad-264).
// Phase 2: in-LDS attention; wave w owns q-frags {w, 15-w} (balanced causal).
__global__ __launch_bounds__(512, 2) void fused_kernel(const float* __restrict__ x,
                             const short* __restrict__ Wt, float* __restrict__ out){
  __shared__ __align__(16) short Qs[256*72];    // 36864 B  (stride 36 dw -> 2-way: free)
  __shared__ __align__(16) short Ks[256*72];    // 36864 B
  __shared__ __align__(16) short Vts[64*264];   // 33792 B  [h][t] stride 132 dw -> 2-way
  __shared__ __align__(16) short Pp[8][16*40];  // 10240 B  per-wave P scratch

  const int tid  = threadIdx.x;
  const int w    = tid >> 6, lane = tid & 63;
  const int l31  = lane & 31, hh = lane >> 5;
  const int b    = blockIdx.x;

  // ================= Phase 1: QKV projection =================
  const float* xb = x + ((long)b*256 + w*32)*384;   // this wave's 32 rows

  f32x16 acc[6];
  #pragma unroll
  for (int c = 0; c < 6; ++c)
    #pragma unroll
    for (int j = 0; j < 16; ++j) acc[c][j] = 0.0f;

  #pragma unroll 2
  for (int kt = 0; kt < 6; ++kt){
    #pragma unroll
    for (int s = 0; s < 4; ++s){
      const int k0 = kt*64 + s*16 + hh*8;
      const float* xp = xb + l31*384 + k0;
      float4 a0 = *(const float4*)xp;
      float4 a1 = *(const float4*)(xp + 4);
      s16x8 bx;                                   // B[k][n=row]: lane l31 = row
      bx[0]=f2bf(a0.x); bx[1]=f2bf(a0.y); bx[2]=f2bf(a0.z); bx[3]=f2bf(a0.w);
      bx[4]=f2bf(a1.x); bx[5]=f2bf(a1.y); bx[6]=f2bf(a1.z); bx[7]=f2bf(a1.w);
      #pragma unroll
      for (int c = 0; c < 6; ++c){                // A[m=outcol][k]: lane l31 = outcol
        s16x8 wa = *(const s16x8*)(Wt + (c*32 + l31)*384 + k0);
        acc[c] = __builtin_amdgcn_mfma_f32_32x32x16_bf16(wa, bx, acc[c], 0, 0, 0);
      }
    }
  }

  // Epilogue: C col(n)=row=l31, rowC(m)=(reg&3)+8*(reg>>2)+4*hh = outcol
  const int trow = w*32 + l31;
  #pragma unroll
  for (int c = 0; c < 4; ++c){                    // Q (c=0,1), K (c=2,3)
    short* dst = (c < 2) ? Qs : Ks;
    const int nb = (c & 1)*32;
    #pragma unroll
    for (int g = 0; g < 4; ++g){                  // 4 consecutive outcols -> b64 write
      s16x4 v;
      #pragma unroll
      for (int i = 0; i < 4; ++i) v[i] = f2bf(acc[c][g*4 + i]);
      *(s16x4*)(dst + trow*72 + nb + 8*g + 4*hh) = v;
    }
  }
  #pragma unroll
  for (int c = 4; c < 6; ++c)                     // V -> Vts[h][t]
    #pragma unroll
    for (int reg = 0; reg < 16; ++reg){
      const int h = (c-4)*32 + (reg & 3) + 8*(reg >> 2) + 4*hh;
      Vts[h*264 + trow] = f2bf(acc[c][reg]);
    }

  __syncthreads();

  // ================= Phase 2: causal attention (all in LDS) =================
  const int l15 = lane & 15, quad = lane >> 4;
  float* ob = out + (long)b*256*64;
  short* Pw = Pp[w];

  for (int it = 0; it < 2; ++it){
    const int F  = it ? (15 - w) : w;             // q-frag (16 queries), wave-uniform
    const int qb = F*16;
    const int NF = F + 1;                         // causal key-frags needed (1..16)
    const int NS = (NF + 1) >> 1;                 // 32-key PV steps

    // A frags: A[m=q][k=quad*8+j]
    s16x8 qf0 = *(const s16x8*)(Qs + (qb + l15)*72 + quad*8);
    s16x8 qf1 = *(const s16x8*)(Qs + (qb + l15)*72 + 32 + quad*8);

    f32x4 sc[16];
    #pragma unroll
    for (int f = 0; f < 16; ++f){
      f32x4 a;
      #pragma unroll
      for (int r = 0; r < 4; ++r) a[r] = 0.0f;
      if (f < NF){
        const short* kp = Ks + (f*16 + l15)*72 + quad*8;  // B[k=h][n=key]
        s16x8 k0v = *(const s16x8*)kp;
        s16x8 k1v = *(const s16x8*)(kp + 32);
        a = __builtin_amdgcn_mfma_f32_16x16x32_bf16(qf0, k0v, a, 0, 0, 0);
        a = __builtin_amdgcn_mfma_f32_16x16x32_bf16(qf1, k1v, a, 0, 0, 0);
      }
      sc[f] = a;
    }

    // softmax: C col=key=f*16+l15, row=q=quad*4+r
    float mx[4], sm[4];
    #pragma unroll
    for (int r = 0; r < 4; ++r) mx[r] = -3.0e38f;
    #pragma unroll
    for (int f = 0; f < 16; ++f){
      if (f < NF){
        const int key = f*16 + l15;
        #pragma unroll
        for (int r = 0; r < 4; ++r){
          const int qg = qb + quad*4 + r;
          float s = sc[f][r] * 0.125f;            // d^-0.5, H=64
          s = (key <= qg) ? s : -1.0e30f;
          sc[f][r] = s;
          mx[r] = fmaxf(mx[r], s);
        }
      }
    }
    #pragma unroll
    for (int r = 0; r < 4; ++r){
      #pragma unroll
      for (int off = 1; off < 16; off <<= 1) mx[r] = fmaxf(mx[r], __shfl_xor(mx[r], off, 16));
    }
    #pragma unroll
    for (int r = 0; r < 4; ++r) sm[r] = 0.0f;
    #pragma unroll
    for (int f = 0; f < 16; ++f){
      if (f < NF){
        #pragma unroll
        for (int r = 0; r < 4; ++r){
          float p = exp2f((sc[f][r] - mx[r]) * 1.44269504f);
          sc[f][r] = p;
          sm[r] += p;
        }
      }
    }
    #pragma unroll
    for (int r = 0; r < 4; ++r){
      #pragma unroll
      for (int off = 1; off < 16; off <<= 1) sm[r] += __shfl_xor(sm[r], off, 16);
    }

    // PV: A = P (LDS round-trip C->A layout), B = Vts rows
    f32x4 o[4];
    #pragma unroll
    for (int h0 = 0; h0 < 4; ++h0)
      #pragma unroll
      for (int r = 0; r < 4; ++r) o[h0][r] = 0.0f;

    #pragma unroll
    for (int ks = 0; ks < 8; ++ks){
      if (ks < NS){
        #pragma unroll
        for (int fi = 0; fi < 2; ++fi){
          const int f = 2*ks + fi;
          #pragma unroll
          for (int r = 0; r < 4; ++r){
            short v = 0;
            if (f < NF) v = f2bf(sc[f][r]);
            Pw[(quad*4 + r)*40 + fi*16 + l15] = v;
          }
        }
        s16x8 pf = *(const s16x8*)(Pw + l15*40 + quad*8);   // A[m=q][k]
        #pragma unroll
        for (int h0 = 0; h0 < 4; ++h0){
          s16x8 vf = *(const s16x8*)(Vts + (h0*16 + l15)*264 + ks*32 + quad*8);
          o[h0] = __builtin_amdgcn_mfma_f32_16x16x32_bf16(pf, vf, o[h0], 0, 0, 0);
        }
      }
    }

    #pragma unroll
    for (int r = 0; r < 4; ++r){
      const float inv = 1.0f / sm[r];
      #pragma unroll
      for (int h0 = 0; h0 < 4; ++h0)
        ob[(qb + quad*4 + r)*64 + h0*16 + l15] = o[h0][r] * inv;
    }
  }
}

extern "C" void kernel_launch(void* const* d_in, const int* in_sizes, int n_in,
                              void* d_out, int out_size, void* d_ws, size_t ws_size,
                              hipStream_t stream){
  const float* x  = (const float*)d_in[0];
  const float* Wq = (const float*)d_in[1];
  const float* Wk = (const float*)d_in[2];
  const float* Wv = (const float*)d_in[3];
  float* out = (float*)d_out;

  short* Wt = (short*)d_ws;                        // 192*384*2 = 147456 B

  hipLaunchKernelGGL(wt_prep_kernel, dim3(288), dim3(256), 0, stream, Wq, Wk, Wv, Wt);
  hipLaunchKernelGGL(fused_kernel,   dim3(512), dim3(512), 0, stream, x, Wt, out);
}